// Round 2
// baseline (16808.658 us; speedup 1.0000x reference)
//
#include <hip/hip_runtime.h>
#include <math.h>

#define BB 16
#define TT 500
#define DD 512
#define NSTEP 128
#define EE 640
#define HHH 1024
#define AAA 1024
#define VV 10025
#define RIN_LD 2176   // H + E + D
#define GX_LD 3072    // i|g|o (f gate is dead: zero-state LSTM)

__device__ __forceinline__ float sigmoidf_(float x){ return 1.0f/(1.0f+expf(-x)); }

__device__ __forceinline__ float wave_sum64(float v){
  #pragma unroll
  for (int off = 32; off; off >>= 1) v += __shfl_down(v, off, 64);
  return v;
}

__global__ void k_zero(float* p, int n){
  int i = blockIdx.x*256 + threadIdx.x;
  if (i < n) p[i] = 0.f;
}

// shifted embedding gather into rin[:, 1024:1664]
__global__ void k_emb(const float* __restrict__ embed, const int* __restrict__ labels,
                      float* __restrict__ rin){
  int bn = blockIdx.x;            // b*128+n
  int n = bn & 127, b = bn >> 7;
  int t = threadIdx.x;
  if (t >= 160) return;           // 160 float4 = 640 floats
  float4 v = make_float4(0.f,0.f,0.f,0.f);
  if (n > 0){
    int lab = labels[b*NSTEP + n - 1];
    v = *(const float4*)(embed + (long)lab*EE + t*4);
  }
  *(float4*)(rin + (long)bn*RIN_LD + HHH + t*4) = v;
}

// C[m,n] = sum_k A[m,k]*W[map(n),k] + bias ; 128x128 tile, 8x8 microtile
template<int MAP>
__global__ __launch_bounds__(256) void gemm_f32(
    const float* __restrict__ A, int lda,
    const float* __restrict__ W, int ldw,
    const float* __restrict__ b0, const float* __restrict__ b1,
    float* __restrict__ C, int ldc, int M, int Ncols, int K)
{
  __shared__ float As[16][132];
  __shared__ float Ws[16][132];
  const int tid = threadIdx.x;
  const int mb = blockIdx.y * 128, nb = blockIdx.x * 128;
  const int lrow = tid >> 1;
  const int lk = (tid & 1) * 8;
  int arow = mb + lrow; if (arow > M-1) arow = M-1;
  int wr = nb + lrow;  if (wr > Ncols-1) wr = Ncols-1;
  const int wrow = MAP ? (wr + ((wr >= 1024) ? 1024 : 0)) : wr;
  const float* Ap = A + (long)arow * lda + lk;
  const float* Wp = W + (long)wrow * ldw + lk;
  const int m0 = (tid >> 4) * 8, n0 = (tid & 15) * 8;
  float acc[8][8];
  #pragma unroll
  for (int i = 0; i < 8; i++)
    #pragma unroll
    for (int j = 0; j < 8; j++) acc[i][j] = 0.f;

  for (int k0 = 0; k0 < K; k0 += 16){
    const float4 a0 = *(const float4*)(Ap + k0);
    const float4 a1 = *(const float4*)(Ap + k0 + 4);
    const float4 w0 = *(const float4*)(Wp + k0);
    const float4 w1 = *(const float4*)(Wp + k0 + 4);
    __syncthreads();
    As[lk+0][lrow]=a0.x; As[lk+1][lrow]=a0.y; As[lk+2][lrow]=a0.z; As[lk+3][lrow]=a0.w;
    As[lk+4][lrow]=a1.x; As[lk+5][lrow]=a1.y; As[lk+6][lrow]=a1.z; As[lk+7][lrow]=a1.w;
    Ws[lk+0][lrow]=w0.x; Ws[lk+1][lrow]=w0.y; Ws[lk+2][lrow]=w0.z; Ws[lk+3][lrow]=w0.w;
    Ws[lk+4][lrow]=w1.x; Ws[lk+5][lrow]=w1.y; Ws[lk+6][lrow]=w1.z; Ws[lk+7][lrow]=w1.w;
    __syncthreads();
    #pragma unroll
    for (int kk = 0; kk < 16; kk++){
      const float4 aa0 = *(const float4*)&As[kk][m0];
      const float4 aa1 = *(const float4*)&As[kk][m0+4];
      const float4 bb0 = *(const float4*)&Ws[kk][n0];
      const float4 bb1 = *(const float4*)&Ws[kk][n0+4];
      const float av[8] = {aa0.x,aa0.y,aa0.z,aa0.w,aa1.x,aa1.y,aa1.z,aa1.w};
      const float bv[8] = {bb0.x,bb0.y,bb0.z,bb0.w,bb1.x,bb1.y,bb1.z,bb1.w};
      #pragma unroll
      for (int i = 0; i < 8; i++)
        #pragma unroll
        for (int j = 0; j < 8; j++)
          acc[i][j] = fmaf(av[i], bv[j], acc[i][j]);
    }
  }
  #pragma unroll
  for (int j = 0; j < 8; j++){
    const int n = nb + n0 + j;
    if (n >= Ncols) continue;
    const int np = MAP ? (n + ((n >= 1024) ? 1024 : 0)) : n;
    float bias = 0.f;
    if (b0) bias += b0[np];
    if (b1) bias += b1[np];
    #pragma unroll
    for (int i = 0; i < 8; i++){
      const int m = mb + m0 + i;
      if (m < M) C[(long)m * ldc + n] = acc[i][j] + bias;
    }
  }
}

// inv_fert_half[b,t] = 0.5*sigmoid(enc[b,t,:] . W_if) ; one wave per (b,t)
__global__ void k_invfert(const float* __restrict__ enc, const float* __restrict__ W_if,
                          float* __restrict__ ifert){
  int gid = blockIdx.x*256 + threadIdx.x;
  int wid = gid >> 6, l = gid & 63;
  if (wid >= BB*TT) return;
  const float* row = enc + (long)wid*DD;
  float4 x0 = *(const float4*)(row + l*8);
  float4 x1 = *(const float4*)(row + l*8 + 4);
  float4 w0 = *(const float4*)(W_if + l*8);
  float4 w1 = *(const float4*)(W_if + l*8 + 4);
  float s = x0.x*w0.x + x0.y*w0.y + x0.z*w0.z + x0.w*w0.w
          + x1.x*w1.x + x1.y*w1.y + x1.z*w1.z + x1.w*w1.w;
  s = wave_sum64(s);
  if (l == 0) ifert[wid] = 0.5f * sigmoidf_(s);
}

// per-step: gates(ctx part) + activations + zoneout-h ; 64 blocks x (16b x 16j)
__global__ __launch_bounds__(256) void k_gate(const float* __restrict__ W_ih,
    const float* __restrict__ gx, float* __restrict__ rin, int n){
  __shared__ float cl[16*516];
  const int tid = threadIdx.x;
  if (n > 0){
    for (int i = tid; i < 16*128; i += 256){
      int b = i >> 7, d4 = (i & 127) * 4;
      *(float4*)&cl[b*516 + d4] =
        *(const float4*)(rin + (long)(b*NSTEP + n-1)*RIN_LD + (HHH+EE) + d4);
    }
  }
  __syncthreads();
  const int b = tid >> 4;
  const int j = blockIdx.x * 16 + (tid & 15);
  const long gxrow = (long)(b*NSTEP + n)*GX_LD;
  float ai = gx[gxrow + j];
  float ag = gx[gxrow + 1024 + j];
  float ao = gx[gxrow + 2048 + j];
  if (n > 0){
    const float* Wi = W_ih + (long)j*1152 + EE;
    const float* Wg = W_ih + (long)(2048 + j)*1152 + EE;
    const float* Wo = W_ih + (long)(3072 + j)*1152 + EE;
    const float* cb = &cl[b*516];
    #pragma unroll 4
    for (int k = 0; k < DD; k += 4){
      float4 c4 = *(const float4*)(cb + k);
      float4 wi = *(const float4*)(Wi + k);
      float4 wg = *(const float4*)(Wg + k);
      float4 wo = *(const float4*)(Wo + k);
      ai += c4.x*wi.x + c4.y*wi.y + c4.z*wi.z + c4.w*wi.w;
      ag += c4.x*wg.x + c4.y*wg.y + c4.z*wg.z + c4.w*wg.w;
      ao += c4.x*wo.x + c4.y*wo.y + c4.z*wo.z + c4.w*wo.w;
    }
  }
  float cn = sigmoidf_(ai) * tanhf(ag);
  float hn = sigmoidf_(ao) * tanhf(cn);
  float h = 0.95f * hn;
  if (n > 0) h += 0.05f * rin[(long)(b*NSTEP + n-1)*RIN_LD + j];
  rin[(long)(b*NSTEP + n)*RIN_LD + j] = h;
}

// per-step: s[b,a] = h[b,:] . W_s[a,:]
__global__ __launch_bounds__(256) void k_s(const float* __restrict__ W_s,
    const float* __restrict__ rin, float* __restrict__ svec, int n){
  __shared__ float hl[16*1028];
  const int tid = threadIdx.x;
  for (int i = tid; i < 16*256; i += 256){
    int b = i >> 8, d4 = (i & 255) * 4;
    *(float4*)&hl[b*1028 + d4] = *(const float4*)(rin + (long)(b*NSTEP + n)*RIN_LD + d4);
  }
  __syncthreads();
  const int b = tid >> 4;
  const int a = blockIdx.x * 16 + (tid & 15);
  const float* Wr = W_s + (long)a*HHH;
  const float* hb = &hl[b*1028];
  float acc = 0.f;
  #pragma unroll 4
  for (int k = 0; k < HHH; k += 4){
    float4 h4 = *(const float4*)(hb + k);
    float4 w4 = *(const float4*)(Wr + k);
    acc += h4.x*w4.x + h4.y*w4.y + h4.z*w4.z + h4.w*w4.w;
  }
  svec[b*AAA + a] = acc;
}

// per-step: e[b,t] = sum_a v[a]*tanh(ectx + s + accum*fb), masked
__global__ __launch_bounds__(256) void k_energy(const float* __restrict__ ectx,
    const float* __restrict__ svec, const float* __restrict__ v_att,
    const float* __restrict__ W_fb, const float* __restrict__ accum,
    const int* __restrict__ slen, float* __restrict__ evec){
  __shared__ float sl[1024], vl[1024], fl[1024];
  const int b = blockIdx.y, tid = threadIdx.x;
  {
    int i = tid*4;
    *(float4*)&sl[i] = *(const float4*)(svec + b*AAA + i);
    *(float4*)&vl[i] = *(const float4*)(v_att + i);
    *(float4*)&fl[i] = *(const float4*)(W_fb + i);
  }
  __syncthreads();
  const int w = tid >> 6, l = tid & 63;
  const int t = blockIdx.x*4 + w;
  const float acc = accum[b*TT + t];
  const float* er = ectx + (long)(b*TT + t)*AAA;
  float e = 0.f;
  #pragma unroll
  for (int q = 0; q < 4; q++){
    int a0 = q*256 + l*4;
    float4 ec = *(const float4*)(er + a0);
    e += vl[a0+0]*tanhf(ec.x + sl[a0+0] + acc*fl[a0+0]);
    e += vl[a0+1]*tanhf(ec.y + sl[a0+1] + acc*fl[a0+1]);
    e += vl[a0+2]*tanhf(ec.z + sl[a0+2] + acc*fl[a0+2]);
    e += vl[a0+3]*tanhf(ec.w + sl[a0+3] + acc*fl[a0+3]);
  }
  e = wave_sum64(e);
  if (l == 0){
    if (t >= slen[b]) e = -INFINITY;
    evec[b*TT + t] = e;
  }
}

// per-step: softmax over t + ctx[b,d] + accum update
__global__ __launch_bounds__(256) void k_ctx(const float* __restrict__ evec,
    const float* __restrict__ enc, const float* __restrict__ ifert,
    float* __restrict__ accum, float* __restrict__ rin, int n){
  __shared__ float wl[TT];
  __shared__ float red[256];
  __shared__ float part[4][64];
  const int b = blockIdx.y, tid = threadIdx.x;
  float e0 = (tid < TT)      ? evec[b*TT + tid]      : -INFINITY;
  float e1 = (tid+256 < TT)  ? evec[b*TT + tid+256]  : -INFINITY;
  red[tid] = fmaxf(e0, e1); __syncthreads();
  for (int s = 128; s; s >>= 1){ if (tid < s) red[tid] = fmaxf(red[tid], red[tid+s]); __syncthreads(); }
  const float mx = red[0]; __syncthreads();
  float p0 = (tid < TT)     ? expf(e0 - mx) : 0.f;
  float p1 = (tid+256 < TT) ? expf(e1 - mx) : 0.f;
  red[tid] = p0 + p1; __syncthreads();
  for (int s = 128; s; s >>= 1){ if (tid < s) red[tid] += red[tid+s]; __syncthreads(); }
  const float inv = 1.f / red[0];
  if (tid < TT)     wl[tid]     = p0 * inv;
  if (tid+256 < TT) wl[tid+256] = p1 * inv;
  __syncthreads();
  if (blockIdx.x == 0){
    if (tid < TT)     accum[b*TT + tid]     += wl[tid]     * ifert[b*TT + tid];
    if (tid+256 < TT) accum[b*TT + tid+256] += wl[tid+256] * ifert[b*TT + tid+256];
  }
  const int w = tid >> 6, l = tid & 63;
  const int d = blockIdx.x*64 + l;
  float acc = 0.f;
  for (int t = w; t < TT; t += 4)
    acc += wl[t] * enc[(long)(b*TT + t)*DD + d];
  part[w][l] = acc; __syncthreads();
  if (w == 0){
    float s = part[0][l] + part[1][l] + part[2][l] + part[3][l];
    rin[(long)(b*NSTEP + n)*RIN_LD + (HHH+EE) + d] = s;
  }
}

// maxout pairs: mo[m,p] = max(ro[m,2p], ro[m,2p+1])
__global__ void k_maxout(const float* __restrict__ ro, float* __restrict__ mo){
  int i = blockIdx.x*256 + threadIdx.x;
  if (i < 2048*512){
    int m = i >> 9, p = i & 511;
    mo[i] = fmaxf(ro[(long)m*1024 + 2*p], ro[(long)m*1024 + 2*p + 1]);
  }
}

extern "C" void kernel_launch(void* const* d_in, const int* in_sizes, int n_in,
                              void* d_out, int out_size, void* d_ws, size_t ws_size,
                              hipStream_t stream)
{
  const float* enc   = (const float*)d_in[0];
  const int*   labels= (const int*)  d_in[1];
  const int*   slen  = (const int*)  d_in[2];
  const float* embed = (const float*)d_in[3];
  const float* W_ih  = (const float*)d_in[4];
  const float* b_ih  = (const float*)d_in[5];
  const float* b_hh  = (const float*)d_in[6];
  const float* W_s   = (const float*)d_in[7];
  const float* W_enc = (const float*)d_in[8];
  const float* b_enc = (const float*)d_in[9];
  const float* v_att = (const float*)d_in[10];
  const float* W_if  = (const float*)d_in[11];
  const float* W_fb  = (const float*)d_in[12];
  const float* W_ro  = (const float*)d_in[13];
  const float* b_ro  = (const float*)d_in[14];
  const float* W_out = (const float*)d_in[15];
  const float* b_out = (const float*)d_in[16];
  float* out = (float*)d_out;

  float* ws   = (float*)d_ws;
  float* rin  = ws;                          // [2048,2176]  h|emb|ctx
  float* gx   = rin  + (long)2048*RIN_LD;    // [2048,3072]  i|g|o  x-part+bias
  float* ectx = gx   + (long)2048*GX_LD;     // [8000,1024]
  float* ifert= ectx + (long)8000*1024;      // [8000]  0.5*sigmoid
  float* accum= ifert+ 8000;                 // [8000]
  float* svec = accum+ 8000;                 // [16,1024]
  float* evec = svec + 16384;                // [8000]
  float* ro   = evec + 8000;                 // [2048,1024]
  float* mo   = ro   + (long)2048*1024;      // [2048,512]

  k_zero<<<32, 256, 0, stream>>>(accum, 8000);
  k_emb<<<2048, 256, 0, stream>>>(embed, labels, rin);
  // gates x-part (+ both biases), f gate skipped via MAP row mapping
  gemm_f32<1><<<dim3(24,16), 256, 0, stream>>>(rin + HHH, RIN_LD, W_ih, 1152,
                                               b_ih, b_hh, gx, GX_LD, 2048, 3072, 640);
  gemm_f32<0><<<dim3(8,63), 256, 0, stream>>>(enc, DD, W_enc, DD,
                                              b_enc, nullptr, ectx, AAA, BB*TT, AAA, DD);
  k_invfert<<<2000, 256, 0, stream>>>(enc, W_if, ifert);

  for (int n = 0; n < NSTEP; n++){
    k_gate  <<<64, 256, 0, stream>>>(W_ih, gx, rin, n);
    k_s     <<<64, 256, 0, stream>>>(W_s, rin, svec, n);
    k_energy<<<dim3(125,16), 256, 0, stream>>>(ectx, svec, v_att, W_fb, accum, slen, evec);
    k_ctx   <<<dim3(8,16), 256, 0, stream>>>(evec, enc, ifert, accum, rin, n);
  }

  gemm_f32<0><<<dim3(8,16), 256, 0, stream>>>(rin, RIN_LD, W_ro, RIN_LD,
                                              b_ro, nullptr, ro, 1024, 2048, 1024, RIN_LD);
  k_maxout<<<4096, 256, 0, stream>>>(ro, mo);
  gemm_f32<0><<<dim3(79,16), 256, 0, stream>>>(mo, 512, W_out, 512,
                                               b_out, nullptr, out, VV, 2048, VV, 512);
}